// Round 1
// baseline (1237.169 us; speedup 1.0000x reference)
//
#include <hip/hip_runtime.h>
#include <hip/hip_bf16.h>
#include <hip/hip_fp16.h>

// 2-layer Elman RNN, S=64 B=64 H=E=512 V=10000.
// Phases: cvt weights->f16, gather X, [GEMM A0=X@W0^T] -> [recur layer0]
//         -> [GEMM B1=H0@W1^T] -> [recur layer1] -> [GEMM logits=H1@Wd^T].
// All MFMA in fp16 (mfma_f32_16x16x32_f16), fp32 accum. Threshold 9.5e-2,
// expected absmax ~1e-2.

typedef _Float16 f16;
typedef _Float16 f16x8 __attribute__((ext_vector_type(8)));
typedef float fvec4 __attribute__((ext_vector_type(4)));
typedef float f32x4 __attribute__((ext_vector_type(4)));

__device__ __forceinline__ f32x4 mfma16(f16x8 a, f16x8 b, f32x4 c) {
    return __builtin_amdgcn_mfma_f32_16x16x32_f16(a, b, c, 0, 0, 0);
}

__device__ __forceinline__ f16x8 cvt_f16x8(fvec4 a, fvec4 b) {
    f16x8 r;
    r[0] = (f16)a[0]; r[1] = (f16)a[1]; r[2] = (f16)a[2]; r[3] = (f16)a[3];
    r[4] = (f16)b[0]; r[5] = (f16)b[1]; r[6] = (f16)b[2]; r[7] = (f16)b[3];
    return r;
}

// ---- fp32 -> f16 convert, 8 elems/thread ----
__global__ void cvt_f32_f16(const float* __restrict__ src, f16* __restrict__ dst, int n8) {
    int i = blockIdx.x * 256 + threadIdx.x;
    if (i >= n8) return;
    const fvec4* p = (const fvec4*)(src + (size_t)i * 8);
    *(f16x8*)(dst + (size_t)i * 8) = cvt_f16x8(p[0], p[1]);
}

// ---- Wd (10000x512) -> f16 padded to 10112 rows (zero pad) ----
__global__ void cvt_wd(const float* __restrict__ src, f16* __restrict__ dst) {
    int i = blockIdx.x * 256 + threadIdx.x;       // chunks of 8; 10112*512/8
    if (i >= 647168) return;
    if (i < 640000) {
        const fvec4* p = (const fvec4*)(src + (size_t)i * 8);
        *(f16x8*)(dst + (size_t)i * 8) = cvt_f16x8(p[0], p[1]);
    } else {
        f16x8 z = {};
        *(f16x8*)(dst + (size_t)i * 8) = z;
    }
}

// ---- gather X = f16(emb[tokens]) : (4096, 512) ----
__global__ void gather_x(const int* __restrict__ toks, const float* __restrict__ emb,
                         f16* __restrict__ xb) {
    int i = blockIdx.x * 256 + threadIdx.x;       // 4096*64 chunks of 8
    if (i >= 262144) return;
    int row = i >> 6, seg = i & 63;
    int tok = toks[row];
    const fvec4* p = (const fvec4*)(emb + (size_t)tok * 512 + seg * 8);
    *(f16x8*)(xb + (size_t)row * 512 + seg * 8) = cvt_f16x8(p[0], p[1]);
}

__global__ void zero_u32(unsigned* p, int n) {
    int i = blockIdx.x * 256 + threadIdx.x;
    if (i < n) p[i] = 0;
}

// ---- GEMM: C(M,N) fp32 = A(M,512)f16 @ Bm(Npad,512)f16 ^T + bias1 + bias2 ----
// 128x128 tile, 4 waves (2x2 quadrants of 64x64), BK=32, reg-staged LDS,
// rows padded to 40 f16 (80B) -> conflict-free-ish ds_read_b128.
__global__ __launch_bounds__(256) void gemm_bt(
    const f16* __restrict__ A, const f16* __restrict__ Bm,
    const float* __restrict__ bias1, const float* __restrict__ bias2,
    float* __restrict__ C, int N)
{
    const int tM = blockIdx.x * 128;
    const int tN = blockIdx.y * 128;
    const int tid = threadIdx.x;
    const int l = tid & 63, w = tid >> 6;
    const int wr = w >> 1, wc = w & 1;
    const int l15 = l & 15, l4 = l >> 4;

    __shared__ f16 As[128 * 40];
    __shared__ f16 Bs[128 * 40];

    f32x4 acc[4][4] = {};

    for (int ks = 0; ks < 16; ++ks) {
        const int k0 = ks * 32;
        __syncthreads();
#pragma unroll
        for (int it = 0; it < 2; ++it) {
            int c = tid + it * 256;               // 512 chunks: row=c>>2, seg=c&3
            int row = c >> 2, seg = c & 3;
            *(f16x8*)(&As[row * 40 + seg * 8]) =
                *(const f16x8*)(A + (size_t)(tM + row) * 512 + k0 + seg * 8);
            *(f16x8*)(&Bs[row * 40 + seg * 8]) =
                *(const f16x8*)(Bm + (size_t)(tN + row) * 512 + k0 + seg * 8);
        }
        __syncthreads();
        f16x8 af[4], bf[4];
#pragma unroll
        for (int m = 0; m < 4; ++m)
            af[m] = *(const f16x8*)(&As[(wr * 64 + m * 16 + l15) * 40 + 8 * l4]);
#pragma unroll
        for (int n = 0; n < 4; ++n)
            bf[n] = *(const f16x8*)(&Bs[(wc * 64 + n * 16 + l15) * 40 + 8 * l4]);
#pragma unroll
        for (int m = 0; m < 4; ++m)
#pragma unroll
            for (int n = 0; n < 4; ++n)
                acc[m][n] = mfma16(af[m], bf[n], acc[m][n]);
    }

    // epilogue: D[row=(l>>4)*4+r][col=l&15] per 16x16 frag (m89-verified layout)
#pragma unroll
    for (int n = 0; n < 4; ++n) {
        int col = tN + wc * 64 + n * 16 + l15;
        if (col >= N) continue;
        float bsum = (bias1 ? bias1[col] : 0.f) + (bias2 ? bias2[col] : 0.f);
#pragma unroll
        for (int m = 0; m < 4; ++m) {
#pragma unroll
            for (int r = 0; r < 4; ++r) {
                int row = tM + wr * 64 + m * 16 + l4 * 4 + r;
                C[(size_t)row * N + col] = acc[m][n][r] + bsum;
            }
        }
    }
}

// ---- Recurrence: h_t = tanh(Ain[t] + h_{t-1} @ U^T) for one layer ----
// Grid 32 blocks = 4 batch-groups (16 rows) x 8 col-slices (64 cols).
// 128 threads = 2 waves, each wave: 2 ntiles of 16 cols, M=16, K=512.
// U fragments preloaded to registers ONCE (constant over t). h staged to LDS
// (row-padded +8 f16) each step. Group-local flag sync (agent scope).
__global__ __launch_bounds__(128, 1) void recur_kernel(
    const float* __restrict__ Ain,   // (4096,512) input-side preactivation (+biases)
    const float* __restrict__ U,     // (512,512) fp32 row-major U[n][k]
    const float* __restrict__ h0,    // (64,512) initial hidden, this layer
    f16* __restrict__ Hh,            // (4096,512) f16 history out
    float* __restrict__ outTail,     // (64,512) fp32 final hidden out
    float* __restrict__ hbuf,        // (4,2,16,512) fp32 double buffer
    unsigned* __restrict__ flags)    // (4,64) step counters (pre-zeroed)
{
    const int g = blockIdx.x >> 3, s = blockIdx.x & 7;
    const int tid = threadIdx.x;
    const int l = tid & 63, w = tid >> 6;
    const int l15 = l & 15, l4 = l >> 4;
    const int colbase = s * 64 + w * 32;

    // preload U fragments: B[k][n]=U[n][k]; lane l, reg j -> U[nt*16+l15][kk*32+8*l4+j]
    f16x8 bf[2][16];
#pragma unroll
    for (int nt = 0; nt < 2; ++nt) {
#pragma unroll
        for (int kk = 0; kk < 16; ++kk) {
            const fvec4* p =
                (const fvec4*)(U + (size_t)(colbase + nt * 16 + l15) * 512 + kk * 32 + 8 * l4);
            bf[nt][kk] = cvt_f16x8(p[0], p[1]);
        }
    }

    __shared__ f16 hs[16 * 520];     // rows padded to 520 f16 (1040B): 2-way banks only

    unsigned* flg = flags + g * 64;
    const float* hinit = h0 + (size_t)g * 16 * 512;
    float* hb = hbuf + (size_t)g * 2 * 16 * 512;

    for (int t = 0; t < 64; ++t) {
        if (t > 0 && tid == 0) {
            while (__hip_atomic_load(&flg[t - 1], __ATOMIC_ACQUIRE,
                                     __HIP_MEMORY_SCOPE_AGENT) < 8u) {
                __builtin_amdgcn_s_sleep(1);
            }
        }
        __syncthreads();
        // stage h_{t-1} (16x512 fp32) -> LDS f16
        const float* src = (t == 0) ? hinit : (hb + ((t - 1) & 1) * (16 * 512));
        for (int c = tid; c < 1024; c += 128) {   // 16B chunks: row=c>>6, seg=c&63
            int row = c >> 6, seg = c & 63;
            const fvec4* p = (const fvec4*)(src + row * 512 + seg * 8);
            *(f16x8*)((char*)hs + row * 1040 + seg * 16) = cvt_f16x8(p[0], p[1]);
        }
        __syncthreads();

        f32x4 acc0 = {}, acc1 = {};
#pragma unroll
        for (int kk = 0; kk < 16; ++kk) {
            f16x8 a = *(const f16x8*)((const char*)hs + l15 * 1040 + kk * 64 + 16 * l4);
            acc0 = mfma16(a, bf[0][kk], acc0);
            acc1 = mfma16(a, bf[1][kk], acc1);
        }

        float* hcur = hb + (t & 1) * (16 * 512);
#pragma unroll
        for (int nt = 0; nt < 2; ++nt) {
            f32x4 acc = nt ? acc1 : acc0;
            int col = colbase + nt * 16 + l15;
#pragma unroll
            for (int r = 0; r < 4; ++r) {
                int m = l4 * 4 + r;
                int grow = t * 64 + g * 16 + m;
                float v = tanhf(acc[r] + Ain[(size_t)grow * 512 + col]);
                Hh[(size_t)grow * 512 + col] = (f16)v;
                hcur[m * 512 + col] = v;
                if (t == 63) outTail[(size_t)(g * 16 + m) * 512 + col] = v;
            }
        }
        __threadfence();             // make this thread's stores device-visible
        __syncthreads();             // all block threads done before release
        if (tid == 0)
            __hip_atomic_fetch_add(&flg[t], 1u, __ATOMIC_RELEASE, __HIP_MEMORY_SCOPE_AGENT);
    }
}

extern "C" void kernel_launch(void* const* d_in, const int* in_sizes, int n_in,
                              void* d_out, int out_size, void* d_ws, size_t ws_size,
                              hipStream_t stream) {
    const int*   toks   = (const int*)d_in[0];
    const float* hidden = (const float*)d_in[1];
    const float* emb    = (const float*)d_in[2];
    const float* W0  = (const float*)d_in[3];
    const float* bW0 = (const float*)d_in[4];
    const float* W1  = (const float*)d_in[5];
    const float* bW1 = (const float*)d_in[6];
    const float* U0  = (const float*)d_in[7];
    const float* bU0 = (const float*)d_in[8];
    const float* U1  = (const float*)d_in[9];
    const float* bU1 = (const float*)d_in[10];
    const float* Wd  = (const float*)d_in[11];
    const float* bd  = (const float*)d_in[12];
    float* out = (float*)d_out;

    // workspace layout (needs ~41.1 MB)
    char* ws = (char*)d_ws;
    f16*   W0h  = (f16*)(ws + 0);               // 512*512*2      = 524288
    f16*   W1h  = (f16*)(ws + 524288);          // 524288
    f16*   Wdh  = (f16*)(ws + 1048576);         // 10112*512*2    = 10354688
    f16*   Xb   = (f16*)(ws + 11403264);        // 4096*512*2     = 4194304
    f16*   H0h  = (f16*)(ws + 15597568);        // 4194304
    f16*   H1h  = (f16*)(ws + 19791872);        // 4194304
    float* A0   = (float*)(ws + 23986176);      // 4096*512*4     = 8388608
    float* B1   = (float*)(ws + 32374784);      // 8388608
    float* hbuf = (float*)(ws + 40763392);      // 4*2*16*512*4   = 262144
    unsigned* flags = (unsigned*)(ws + 41025536); // 2*4*64*4     = 2048

    cvt_f32_f16<<<128, 256, 0, stream>>>(W0, W0h, 32768);
    cvt_f32_f16<<<128, 256, 0, stream>>>(W1, W1h, 32768);
    cvt_wd<<<2528, 256, 0, stream>>>(Wd, Wdh);
    gather_x<<<1024, 256, 0, stream>>>(toks, emb, Xb);
    zero_u32<<<2, 256, 0, stream>>>(flags, 512);

    // A0 = X @ W0^T + (bW0 + bU0)
    gemm_bt<<<dim3(32, 4), 256, 0, stream>>>(Xb, W0h, bW0, bU0, A0, 512);
    // layer 0 recurrence -> H0h, final h0 -> out tail
    recur_kernel<<<32, 128, 0, stream>>>(A0, U0, hidden, H0h,
                                         out + 40960000, hbuf, flags);
    // B1 = H0 @ W1^T + (bW1 + bU1)
    gemm_bt<<<dim3(32, 4), 256, 0, stream>>>(H0h, W1h, bW1, bU1, B1, 512);
    // layer 1 recurrence -> H1h, final h1 -> out tail
    recur_kernel<<<32, 128, 0, stream>>>(B1, U1, hidden + 32768, H1h,
                                         out + 40960000 + 32768, hbuf, flags + 256);
    // logits = H1 @ Wd^T + bd
    gemm_bt<<<dim3(32, 79), 256, 0, stream>>>(H1h, Wdh, bd, nullptr, out, 10000);
}

// Round 2
// 484.856 us; speedup vs baseline: 2.5516x; 2.5516x over previous
//
#include <hip/hip_runtime.h>
#include <hip/hip_bf16.h>
#include <hip/hip_fp16.h>

// 2-layer Elman RNN, S=64 B=64 H=E=512 V=10000.
// Phases: cvt weights->f16, gather X, [GEMM A0=X@W0^T] -> [recur layer0]
//         -> [GEMM B1=H0@W1^T] -> [recur layer1] -> [GEMM logits=H1@Wd^T].
// Recurrence: 4 independent blocks (16 batch rows each), ZERO inter-block
// sync. U resident per block: kk 0..11 in VGPRs (192/wave), kk 12..15 in LDS.
// h lives in LDS between steps. All MFMA fp16 (16x16x32), fp32 accum.

typedef _Float16 f16;
typedef _Float16 f16x8 __attribute__((ext_vector_type(8)));
typedef float fvec4 __attribute__((ext_vector_type(4)));
typedef float f32x4 __attribute__((ext_vector_type(4)));

__device__ __forceinline__ f32x4 mfma16(f16x8 a, f16x8 b, f32x4 c) {
    return __builtin_amdgcn_mfma_f32_16x16x32_f16(a, b, c, 0, 0, 0);
}

__device__ __forceinline__ f16x8 cvt_f16x8(fvec4 a, fvec4 b) {
    f16x8 r;
    r[0] = (f16)a[0]; r[1] = (f16)a[1]; r[2] = (f16)a[2]; r[3] = (f16)a[3];
    r[4] = (f16)b[0]; r[5] = (f16)b[1]; r[6] = (f16)b[2]; r[7] = (f16)b[3];
    return r;
}

// ---- fp32 -> f16 convert, 8 elems/thread ----
__global__ void cvt_f32_f16(const float* __restrict__ src, f16* __restrict__ dst, int n8) {
    int i = blockIdx.x * 256 + threadIdx.x;
    if (i >= n8) return;
    const fvec4* p = (const fvec4*)(src + (size_t)i * 8);
    *(f16x8*)(dst + (size_t)i * 8) = cvt_f16x8(p[0], p[1]);
}

// ---- Wd (10000x512) -> f16 padded to 10112 rows (zero pad) ----
__global__ void cvt_wd(const float* __restrict__ src, f16* __restrict__ dst) {
    int i = blockIdx.x * 256 + threadIdx.x;       // chunks of 8; 10112*512/8
    if (i >= 647168) return;
    if (i < 640000) {
        const fvec4* p = (const fvec4*)(src + (size_t)i * 8);
        *(f16x8*)(dst + (size_t)i * 8) = cvt_f16x8(p[0], p[1]);
    } else {
        f16x8 z = {};
        *(f16x8*)(dst + (size_t)i * 8) = z;
    }
}

// ---- gather X = f16(emb[tokens]) : (4096, 512) ----
__global__ void gather_x(const int* __restrict__ toks, const float* __restrict__ emb,
                         f16* __restrict__ xb) {
    int i = blockIdx.x * 256 + threadIdx.x;       // 4096*64 chunks of 8
    if (i >= 262144) return;
    int row = i >> 6, seg = i & 63;
    int tok = toks[row];
    const fvec4* p = (const fvec4*)(emb + (size_t)tok * 512 + seg * 8);
    *(f16x8*)(xb + (size_t)row * 512 + seg * 8) = cvt_f16x8(p[0], p[1]);
}

// ---- GEMM: C(M,N) fp32 = A(M,512)f16 @ Bm(Npad,512)f16 ^T + bias1 + bias2 ----
__global__ __launch_bounds__(256) void gemm_bt(
    const f16* __restrict__ A, const f16* __restrict__ Bm,
    const float* __restrict__ bias1, const float* __restrict__ bias2,
    float* __restrict__ C, int N)
{
    const int tM = blockIdx.x * 128;
    const int tN = blockIdx.y * 128;
    const int tid = threadIdx.x;
    const int l = tid & 63, w = tid >> 6;
    const int wr = w >> 1, wc = w & 1;
    const int l15 = l & 15, l4 = l >> 4;

    __shared__ f16 As[128 * 40];
    __shared__ f16 Bs[128 * 40];

    f32x4 acc[4][4] = {};

    for (int ks = 0; ks < 16; ++ks) {
        const int k0 = ks * 32;
        __syncthreads();
#pragma unroll
        for (int it = 0; it < 2; ++it) {
            int c = tid + it * 256;               // 512 chunks: row=c>>2, seg=c&3
            int row = c >> 2, seg = c & 3;
            *(f16x8*)(&As[row * 40 + seg * 8]) =
                *(const f16x8*)(A + (size_t)(tM + row) * 512 + k0 + seg * 8);
            *(f16x8*)(&Bs[row * 40 + seg * 8]) =
                *(const f16x8*)(Bm + (size_t)(tN + row) * 512 + k0 + seg * 8);
        }
        __syncthreads();
        f16x8 af[4], bf[4];
#pragma unroll
        for (int m = 0; m < 4; ++m)
            af[m] = *(const f16x8*)(&As[(wr * 64 + m * 16 + l15) * 40 + 8 * l4]);
#pragma unroll
        for (int n = 0; n < 4; ++n)
            bf[n] = *(const f16x8*)(&Bs[(wc * 64 + n * 16 + l15) * 40 + 8 * l4]);
#pragma unroll
        for (int m = 0; m < 4; ++m)
#pragma unroll
            for (int n = 0; n < 4; ++n)
                acc[m][n] = mfma16(af[m], bf[n], acc[m][n]);
    }

#pragma unroll
    for (int n = 0; n < 4; ++n) {
        int col = tN + wc * 64 + n * 16 + l15;
        if (col >= N) continue;
        float bsum = (bias1 ? bias1[col] : 0.f) + (bias2 ? bias2[col] : 0.f);
#pragma unroll
        for (int m = 0; m < 4; ++m) {
#pragma unroll
            for (int r = 0; r < 4; ++r) {
                int row = tM + wr * 64 + m * 16 + l4 * 4 + r;
                C[(size_t)row * N + col] = acc[m][n][r] + bsum;
            }
        }
    }
}

// ---- Recurrence: h_t = tanh(Ain[t] + h_{t-1} @ U^T), one block per 16 rows ----
// Grid 4 blocks x 512 threads (8 waves). Wave w owns cols [w*64, w*64+64).
// U f16 frags: kk 0..11 in registers (192 VGPR/wave = 384 KB/block),
// kk 12..15 in LDS (128 KB). h (16x512 f16) in LDS between steps.
// No inter-block communication at all.
__global__ __launch_bounds__(512, 2) void recur_kernel(
    const float* __restrict__ Ain,   // (4096,512) input-side preactivation (+biases)
    const float* __restrict__ U,     // (512,512) fp32 row-major U[n][k]
    const float* __restrict__ h0,    // (64,512) initial hidden, this layer
    f16* __restrict__ Hh,            // (4096,512) f16 history out
    float* __restrict__ outTail)     // (64,512) fp32 final hidden out
{
    const int g = blockIdx.x;            // batch group: rows [g*16, +16)
    const int tid = threadIdx.x;
    const int l = tid & 63, w = tid >> 6;
    const int l15 = l & 15, l4 = l >> 4;
    const int colbase = w * 64;

    __shared__ __align__(16) char smem[17408 + 131072];
    f16*  hs   = (f16*)smem;             // 16 rows x 544 f16 (1088 B rows)
    char* ldsB = smem + 17408;           // [w][nt][kk-12][lane] x 16 B

    // ---- one-time: U fragments (lane l: U[colbase+nt*16+l15][kk*32+8*l4 ..]) ----
    f16x8 bf[4][12];
#pragma unroll
    for (int nt = 0; nt < 4; ++nt) {
        const float* urow = U + (size_t)(colbase + nt * 16 + l15) * 512 + 8 * l4;
#pragma unroll
        for (int kk = 0; kk < 12; ++kk) {
            const fvec4* p = (const fvec4*)(urow + kk * 32);
            bf[nt][kk] = cvt_f16x8(p[0], p[1]);
        }
#pragma unroll
        for (int kk = 12; kk < 16; ++kk) {
            const fvec4* p = (const fvec4*)(urow + kk * 32);
            *(f16x8*)(ldsB + ((w * 4 + nt) * 4 + (kk - 12)) * 1024 + l * 16) =
                cvt_f16x8(p[0], p[1]);
        }
    }
    // ---- one-time: stage h_init ----
    for (int c = tid; c < 1024; c += 512) {
        int row = c >> 6, seg = c & 63;
        const fvec4* p = (const fvec4*)(h0 + (size_t)(g * 16 + row) * 512 + seg * 8);
        *(f16x8*)((char*)hs + row * 1088 + seg * 16) = cvt_f16x8(p[0], p[1]);
    }
    __syncthreads();

    for (int t = 0; t < 64; ++t) {
        // prefetch input-side preactivation (independent of h -> overlaps MFMAs)
        float ain[16];
        const float* abase = Ain + ((size_t)t * 64 + g * 16) * 512;
#pragma unroll
        for (int nt = 0; nt < 4; ++nt)
#pragma unroll
            for (int r = 0; r < 4; ++r)
                ain[nt * 4 + r] = abase[(l4 * 4 + r) * 512 + colbase + nt * 16 + l15];

        f32x4 acc[4] = {};
        const char* arow = (const char*)hs + l15 * 1088 + l4 * 16;
#pragma unroll
        for (int kk = 0; kk < 12; ++kk) {
            f16x8 a = *(const f16x8*)(arow + kk * 64);
            acc[0] = mfma16(a, bf[0][kk], acc[0]);
            acc[1] = mfma16(a, bf[1][kk], acc[1]);
            acc[2] = mfma16(a, bf[2][kk], acc[2]);
            acc[3] = mfma16(a, bf[3][kk], acc[3]);
        }
#pragma unroll
        for (int kk = 12; kk < 16; ++kk) {
            f16x8 a = *(const f16x8*)(arow + kk * 64);
#pragma unroll
            for (int nt = 0; nt < 4; ++nt) {
                f16x8 b = *(const f16x8*)(ldsB + ((w * 4 + nt) * 4 + (kk - 12)) * 1024 + l * 16);
                acc[nt] = mfma16(a, b, acc[nt]);
            }
        }

        // tanh(x) = 1 - 2/(e^{2x}+1) via v_exp + v_rcp (err ~1e-6 << f16 ulp)
#pragma unroll
        for (int nt = 0; nt < 4; ++nt)
#pragma unroll
            for (int r = 0; r < 4; ++r) {
                float x = acc[nt][r] + ain[nt * 4 + r];
                float e = __expf(2.0f * x);
                ain[nt * 4 + r] = 1.0f - 2.0f * __builtin_amdgcn_rcpf(e + 1.0f);
            }

        __syncthreads();                 // everyone done reading h_{t-1}
#pragma unroll
        for (int nt = 0; nt < 4; ++nt)
#pragma unroll
            for (int r = 0; r < 4; ++r)
                hs[(l4 * 4 + r) * 544 + colbase + nt * 16 + l15] = (f16)ain[nt * 4 + r];
        __syncthreads();                 // h_t staged

        // history write, coalesced 16B stores from LDS (overlaps next step)
        f16* hrow = Hh + ((size_t)t * 64 + g * 16) * 512;
        for (int c = tid; c < 1024; c += 512) {
            int row = c >> 6, seg = c & 63;
            *(f16x8*)(hrow + (size_t)row * 512 + seg * 8) =
                *(const f16x8*)((const char*)hs + row * 1088 + seg * 16);
        }
        if (t == 63) {
#pragma unroll
            for (int nt = 0; nt < 4; ++nt)
#pragma unroll
                for (int r = 0; r < 4; ++r)
                    outTail[(size_t)(g * 16 + l4 * 4 + r) * 512 + colbase + nt * 16 + l15] =
                        ain[nt * 4 + r];
        }
    }
}

extern "C" void kernel_launch(void* const* d_in, const int* in_sizes, int n_in,
                              void* d_out, int out_size, void* d_ws, size_t ws_size,
                              hipStream_t stream) {
    const int*   toks   = (const int*)d_in[0];
    const float* hidden = (const float*)d_in[1];
    const float* emb    = (const float*)d_in[2];
    const float* W0  = (const float*)d_in[3];
    const float* bW0 = (const float*)d_in[4];
    const float* W1  = (const float*)d_in[5];
    const float* bW1 = (const float*)d_in[6];
    const float* U0  = (const float*)d_in[7];
    const float* bU0 = (const float*)d_in[8];
    const float* U1  = (const float*)d_in[9];
    const float* bU1 = (const float*)d_in[10];
    const float* Wd  = (const float*)d_in[11];
    const float* bd  = (const float*)d_in[12];
    float* out = (float*)d_out;

    // workspace layout (~40.8 MB)
    char* ws = (char*)d_ws;
    f16*   W0h  = (f16*)(ws + 0);               // 512*512*2      = 524288
    f16*   W1h  = (f16*)(ws + 524288);          // 524288
    f16*   Wdh  = (f16*)(ws + 1048576);         // 10112*512*2    = 10354688
    f16*   Xb   = (f16*)(ws + 11403264);        // 4096*512*2     = 4194304
    f16*   H0h  = (f16*)(ws + 15597568);        // 4194304
    f16*   H1h  = (f16*)(ws + 19791872);        // 4194304
    float* A0   = (float*)(ws + 23986176);      // 4096*512*4     = 8388608
    float* B1   = (float*)(ws + 32374784);      // 8388608

    cvt_f32_f16<<<128, 256, 0, stream>>>(W0, W0h, 32768);
    cvt_f32_f16<<<128, 256, 0, stream>>>(W1, W1h, 32768);
    cvt_wd<<<2528, 256, 0, stream>>>(Wd, Wdh);
    gather_x<<<1024, 256, 0, stream>>>(toks, emb, Xb);

    // A0 = X @ W0^T + (bW0 + bU0)
    gemm_bt<<<dim3(32, 4), 256, 0, stream>>>(Xb, W0h, bW0, bU0, A0, 512);
    // layer 0 recurrence -> H0h, final h0 -> out tail
    recur_kernel<<<4, 512, 0, stream>>>(A0, U0, hidden, H0h, out + 40960000);
    // B1 = H0 @ W1^T + (bW1 + bU1)
    gemm_bt<<<dim3(32, 4), 256, 0, stream>>>(H0h, W1h, bW1, bU1, B1, 512);
    // layer 1 recurrence -> H1h, final h1 -> out tail
    recur_kernel<<<4, 512, 0, stream>>>(B1, U1, hidden + 32768, H1h,
                                        out + 40960000 + 32768);
    // logits = H1 @ Wd^T + bd
    gemm_bt<<<dim3(32, 79), 256, 0, stream>>>(H1h, Wdh, bd, nullptr, out, 10000);
}